// Round 8
// baseline (53.349 us; speedup 1.0000x reference)
//
#include <hip/hip_runtime.h>

#define NB    128           // DTW block size N
#define NCH   64            // channels
#define ROWB  256           // bytes per D row: 128 h16
#define PAIRB 32768         // bytes per pair's D matrix
#define LOG2E 1.4426950408889634f
#define LN2   0.6931471805599453f
#define LARGE 1e9f

typedef _Float16 h16;
typedef __attribute__((ext_vector_type(2))) _Float16 h16x2;
typedef __attribute__((ext_vector_type(8))) _Float16 h16x8;
typedef __attribute__((ext_vector_type(4))) float    f32x4;

static __device__ __forceinline__ float ex2(float x) {
#if __has_builtin(__builtin_amdgcn_exp2f)
    return __builtin_amdgcn_exp2f(x);
#else
    return exp2f(x);
#endif
}

static __device__ __forceinline__ float lg2(float x) {
#if __has_builtin(__builtin_amdgcn_logf)
    return __builtin_amdgcn_logf(x);   // v_log_f32 = log2
#else
    return log2f(x);
#endif
}

// lane t gets lane t-1's src; lane 0 gets `fill`. Pure VALU (DPP wave_shr:1).
static __device__ __forceinline__ float shift_up1(float src, float fill) {
    int r = __builtin_amdgcn_update_dpp(__builtin_bit_cast(int, fill),
                                        __builtin_bit_cast(int, src),
                                        0x138 /*wave_shr:1*/, 0xf, 0xf, false);
    return __builtin_bit_cast(float, r);
}

// soft-min of 3 in log2 domain + D*log2e (gamma=1, exact w.r.t. reference).
static __device__ __forceinline__ float softmin3(float a, float b, float c, float Dv) {
    float m = fminf(fminf(a, b), c);
    float M = fmaxf(fmaxf(a, b), c);
#if __has_builtin(__builtin_amdgcn_fmed3f)
    float e = __builtin_amdgcn_fmed3f(a, b, c);
#else
    float e = ((a + b) + c) - m - M;
#endif
    float s = 1.0f + (ex2(m - e) + ex2(m - M));
    return fmaf(Dv, LOG2E, m - lg2(s));
}

// ============================================================================
// Kernel 1: build D = ||x_i||^2 + ||y_j||^2 - 2 x.y^T per pair (MFMA),
// transpose via LDS, stream to d_ws as fp16 rows (coalesced 1KB/instr).
// ============================================================================
__global__ __launch_bounds__(64, 1)
void dtw_build(const float* __restrict__ X, const float* __restrict__ Y,
               h16* __restrict__ Dws)
{
    __shared__ h16 sD[NB * (ROWB / 2)];     // 32768 B

    const int w = blockIdx.x;
    const int t = threadIdx.x;
    const int c = t & 15, g = t >> 4;
    char* sDb = (char*)sD;
    const float* gx = X + (size_t)w * (NB * NCH);
    const float* gy = Y + (size_t)w * (NB * NCH);

    // B fragments (y as MFMA B) + y2 norms in registers
    h16x8 Bf[8][2];
    float y2r[8];
    #pragma unroll
    for (int J = 0; J < 8; ++J) {
        const float* py = gy + (16 * J + c) * NCH + 8 * g;
        float p = 0.f;
        #pragma unroll
        for (int q = 0; q < 2; ++q) {
            float4 a = *(const float4*)(py + 32 * q);
            float4 b = *(const float4*)(py + 32 * q + 4);
            h16x8 h;
            h[0]=(h16)a.x; h[1]=(h16)a.y; h[2]=(h16)a.z; h[3]=(h16)a.w;
            h[4]=(h16)b.x; h[5]=(h16)b.y; h[6]=(h16)b.z; h[7]=(h16)b.w;
            Bf[J][q] = h;
            p = fmaf(a.x,a.x,p); p = fmaf(a.y,a.y,p);
            p = fmaf(a.z,a.z,p); p = fmaf(a.w,a.w,p);
            p = fmaf(b.x,b.x,p); p = fmaf(b.y,b.y,p);
            p = fmaf(b.z,b.z,p); p = fmaf(b.w,b.w,p);
        }
        p += __shfl_xor(p, 16, 64);
        p += __shfl_xor(p, 32, 64);
        y2r[J] = p;
    }

    float4 nx0, nx1, nx2, nx3;
    {
        const float* px = gx + c * NCH + 8 * g;
        nx0 = *(const float4*)(px);
        nx1 = *(const float4*)(px + 4);
        nx2 = *(const float4*)(px + 32);
        nx3 = *(const float4*)(px + 36);
    }

    #pragma unroll
    for (int I = 0; I < 8; ++I) {
        float4 a0 = nx0, a1 = nx1, a2 = nx2, a3 = nx3;
        if (I < 7) {
            const float* px = gx + (16 * (I + 1) + c) * NCH + 8 * g;
            nx0 = *(const float4*)(px);
            nx1 = *(const float4*)(px + 4);
            nx2 = *(const float4*)(px + 32);
            nx3 = *(const float4*)(px + 36);
        }
        h16x8 Af0, Af1;
        Af0[0]=(h16)a0.x; Af0[1]=(h16)a0.y; Af0[2]=(h16)a0.z; Af0[3]=(h16)a0.w;
        Af0[4]=(h16)a1.x; Af0[5]=(h16)a1.y; Af0[6]=(h16)a1.z; Af0[7]=(h16)a1.w;
        Af1[0]=(h16)a2.x; Af1[1]=(h16)a2.y; Af1[2]=(h16)a2.z; Af1[3]=(h16)a2.w;
        Af1[4]=(h16)a3.x; Af1[5]=(h16)a3.y; Af1[6]=(h16)a3.z; Af1[7]=(h16)a3.w;
        float p = 0.f;
        p=fmaf(a0.x,a0.x,p); p=fmaf(a0.y,a0.y,p); p=fmaf(a0.z,a0.z,p); p=fmaf(a0.w,a0.w,p);
        p=fmaf(a1.x,a1.x,p); p=fmaf(a1.y,a1.y,p); p=fmaf(a1.z,a1.z,p); p=fmaf(a1.w,a1.w,p);
        p=fmaf(a2.x,a2.x,p); p=fmaf(a2.y,a2.y,p); p=fmaf(a2.z,a2.z,p); p=fmaf(a2.w,a2.w,p);
        p=fmaf(a3.x,a3.x,p); p=fmaf(a3.y,a3.y,p); p=fmaf(a3.z,a3.z,p); p=fmaf(a3.w,a3.w,p);
        p += __shfl_xor(p, 16, 64);
        p += __shfl_xor(p, 32, 64);
        float xa[4];
        xa[0] = __shfl(p, 4 * g + 0, 64);
        xa[1] = __shfl(p, 4 * g + 1, 64);
        xa[2] = __shfl(p, 4 * g + 2, 64);
        xa[3] = __shfl(p, 4 * g + 3, 64);

        f32x4 acc[8];
        #pragma unroll
        for (int J = 0; J < 8; ++J) {
            f32x4 z = {0.f, 0.f, 0.f, 0.f};
            z = __builtin_amdgcn_mfma_f32_16x16x32_f16(Af0, Bf[J][0], z, 0, 0, 0);
            z = __builtin_amdgcn_mfma_f32_16x16x32_f16(Af1, Bf[J][1], z, 0, 0, 0);
            acc[J] = z;
        }
        #pragma unroll
        for (int J = 0; J < 8; ++J) {
            char* base = sDb + 2 * (16 * J + c) + ROWB * (16 * I + 4 * g);
            float y2v = y2r[J];
            #pragma unroll
            for (int r = 0; r < 4; ++r) {
                float dv = fmaf(-2.0f, acc[J][r], xa[r] + y2v);
                *(h16*)(base + ROWB * r) = (h16)dv;
            }
        }
    }

    // LDS -> global, coalesced: per u, 64 lanes x 16B = contiguous 1KB
    char* dst = (char*)Dws + (size_t)w * PAIRB;
    #pragma unroll
    for (int u = 0; u < 32; ++u) {
        uint4 v = *(const uint4*)(sDb + 1024 * u + 16 * t);
        *(uint4*)(dst + 1024 * u + 16 * t) = v;
    }
}

// ============================================================================
// Kernel 2: DP only. No LDS, no barriers. D chunks prefetched global->reg.
// Lane t owns rows 2t (state a) and 2t+1 (state b); log2-domain R~ = R*log2e.
// Window: chunk cc, fA[k] = D[2t][16cc+k-2t] at byte 508t + 32cc + 2k.
// All reads land inside the pair's fully-written 32KB block (real D >= 0).
// ============================================================================
__global__ __launch_bounds__(64, 1)
void dtw_dp(const h16* __restrict__ Dws, float* __restrict__ out, int nbpb)
{
    const int w = blockIdx.x;
    const int t = threadIdx.x;
    const char* P = (const char*)Dws + (size_t)w * PAIRB;
    const int baseA = 508 * t;
    const int baseB = 508 * t + 256;

    unsigned cA[8], cB[8], pA[8], pB[8];
    #define GLOAD(dst, off) { _Pragma("unroll") for (int q = 0; q < 8; ++q) \
        (dst)[q] = *(const unsigned*)(P + (off) + 4 * q); }

    GLOAD(cA, baseA)
    GLOAD(cB, baseB)

    float fA[16], fB[16];
    float r1a = LARGE, r1b = LARGE, r2a = LARGE;
    float dg_prev = (t == 0) ? 0.0f : LARGE;   // corner R[-1][-1]=0 feeds cell (0,0)
    float carryB = 0.0f;

    #define CONVERT(sa, sb) { _Pragma("unroll") for (int q = 0; q < 8; ++q) { \
        h16x2 va = __builtin_bit_cast(h16x2, (sa)[q]); \
        h16x2 vb = __builtin_bit_cast(h16x2, (sb)[q]); \
        fA[2*q] = (float)va[0]; fA[2*q+1] = (float)va[1]; \
        fB[2*q] = (float)vb[0]; fB[2*q+1] = (float)vb[1]; } }

    #define STEP(D0v, D1v) { \
        float up_cur = shift_up1(r1b, LARGE); \
        float n0 = softmin3(r1a, up_cur, dg_prev, (D0v)); \
        float n1 = softmin3(r1b, r1a, r2a, (D1v)); \
        r2a = r1a; r1a = n0; r1b = n1; dg_prev = up_cur; }

    #define BODY(curA, curB, nxtA, nxtB, ccv) { \
        if ((ccv) < 15) { \
            GLOAD(nxtA, baseA + 32 * ((ccv) + 1)) \
            GLOAD(nxtB, baseB + 32 * ((ccv) + 1)) \
        } \
        CONVERT(curA, curB) \
        const int kmax = ((ccv) == 15) ? 15 : 16; \
        _Pragma("unroll") \
        for (int k = 0; k < 16; ++k) { \
            if (k < kmax) { \
                float D1v = (k == 0) ? carryB : fB[k - 1]; \
                STEP(fA[k], D1v) \
            } \
        } \
        carryB = fB[15]; }

    #pragma unroll
    for (int cc = 0; cc < 16; cc += 2) {
        BODY(cA, cB, pA, pB, cc)
        BODY(pA, pB, cA, cB, cc + 1)
    }

    if (t == 63) {
        atomicAdd(&out[w / nbpb], r1b * LN2);   // back to natural-log domain
    }
}

// ============================================================================
// Fallback: verified round-7 fused single kernel (used if ws too small)
// ============================================================================
__global__ __launch_bounds__(64, 1)
void dtw_k(const float* __restrict__ X, const float* __restrict__ Y,
           float* __restrict__ out, int nbpb)
{
    __shared__ h16 sD[NB * (ROWB / 2)];

    const int w = blockIdx.x;
    const int t = threadIdx.x;
    const int c = t & 15, g = t >> 4;
    char* sDb = (char*)sD;
    const float* gx = X + (size_t)w * (NB * NCH);
    const float* gy = Y + (size_t)w * (NB * NCH);

    {
        uint4 zz = {0u, 0u, 0u, 0u};
        #pragma unroll
        for (int i = 0; i < 32; ++i)
            *(uint4*)(sDb + 1024 * i + 16 * t) = zz;
    }

    h16x8 Bf[8][2];
    float y2r[8];
    #pragma unroll
    for (int J = 0; J < 8; ++J) {
        const float* py = gy + (16 * J + c) * NCH + 8 * g;
        float p = 0.f;
        #pragma unroll
        for (int q = 0; q < 2; ++q) {
            float4 a = *(const float4*)(py + 32 * q);
            float4 b = *(const float4*)(py + 32 * q + 4);
            h16x8 h;
            h[0]=(h16)a.x; h[1]=(h16)a.y; h[2]=(h16)a.z; h[3]=(h16)a.w;
            h[4]=(h16)b.x; h[5]=(h16)b.y; h[6]=(h16)b.z; h[7]=(h16)b.w;
            Bf[J][q] = h;
            p = fmaf(a.x,a.x,p); p = fmaf(a.y,a.y,p);
            p = fmaf(a.z,a.z,p); p = fmaf(a.w,a.w,p);
            p = fmaf(b.x,b.x,p); p = fmaf(b.y,b.y,p);
            p = fmaf(b.z,b.z,p); p = fmaf(b.w,b.w,p);
        }
        p += __shfl_xor(p, 16, 64);
        p += __shfl_xor(p, 32, 64);
        y2r[J] = p;
    }

    float4 nx0, nx1, nx2, nx3;
    {
        const float* px = gx + c * NCH + 8 * g;
        nx0 = *(const float4*)(px);
        nx1 = *(const float4*)(px + 4);
        nx2 = *(const float4*)(px + 32);
        nx3 = *(const float4*)(px + 36);
    }

    #define TILE(Iexp) { \
        const int I_ = (Iexp); \
        float4 a0 = nx0, a1 = nx1, a2 = nx2, a3 = nx3; \
        if (I_ < 7) { \
            const float* px = gx + (16 * (I_ + 1) + c) * NCH + 8 * g; \
            nx0 = *(const float4*)(px); \
            nx1 = *(const float4*)(px + 4); \
            nx2 = *(const float4*)(px + 32); \
            nx3 = *(const float4*)(px + 36); \
        } \
        h16x8 Af0, Af1; \
        Af0[0]=(h16)a0.x; Af0[1]=(h16)a0.y; Af0[2]=(h16)a0.z; Af0[3]=(h16)a0.w; \
        Af0[4]=(h16)a1.x; Af0[5]=(h16)a1.y; Af0[6]=(h16)a1.z; Af0[7]=(h16)a1.w; \
        Af1[0]=(h16)a2.x; Af1[1]=(h16)a2.y; Af1[2]=(h16)a2.z; Af1[3]=(h16)a2.w; \
        Af1[4]=(h16)a3.x; Af1[5]=(h16)a3.y; Af1[6]=(h16)a3.z; Af1[7]=(h16)a3.w; \
        float p_ = 0.f; \
        p_=fmaf(a0.x,a0.x,p_); p_=fmaf(a0.y,a0.y,p_); p_=fmaf(a0.z,a0.z,p_); p_=fmaf(a0.w,a0.w,p_); \
        p_=fmaf(a1.x,a1.x,p_); p_=fmaf(a1.y,a1.y,p_); p_=fmaf(a1.z,a1.z,p_); p_=fmaf(a1.w,a1.w,p_); \
        p_=fmaf(a2.x,a2.x,p_); p_=fmaf(a2.y,a2.y,p_); p_=fmaf(a2.z,a2.z,p_); p_=fmaf(a2.w,a2.w,p_); \
        p_=fmaf(a3.x,a3.x,p_); p_=fmaf(a3.y,a3.y,p_); p_=fmaf(a3.z,a3.z,p_); p_=fmaf(a3.w,a3.w,p_); \
        p_ += __shfl_xor(p_, 16, 64); \
        p_ += __shfl_xor(p_, 32, 64); \
        float xa_[4]; \
        xa_[0] = __shfl(p_, 4 * g + 0, 64); \
        xa_[1] = __shfl(p_, 4 * g + 1, 64); \
        xa_[2] = __shfl(p_, 4 * g + 2, 64); \
        xa_[3] = __shfl(p_, 4 * g + 3, 64); \
        f32x4 acc_[8]; \
        _Pragma("unroll") \
        for (int J = 0; J < 8; ++J) { \
            f32x4 z = {0.f, 0.f, 0.f, 0.f}; \
            z = __builtin_amdgcn_mfma_f32_16x16x32_f16(Af0, Bf[J][0], z, 0, 0, 0); \
            z = __builtin_amdgcn_mfma_f32_16x16x32_f16(Af1, Bf[J][1], z, 0, 0, 0); \
            acc_[J] = z; \
        } \
        _Pragma("unroll") \
        for (int J = 0; J < 8; ++J) { \
            char* base_ = sDb + 2 * (16 * J + c) + ROWB * (16 * I_ + 4 * g); \
            float y2v_ = y2r[J]; \
            _Pragma("unroll") \
            for (int r = 0; r < 4; ++r) { \
                float dv_ = fmaf(-2.0f, acc_[J][r], xa_[r] + y2v_); \
                *(h16*)(base_ + ROWB * r) = (h16)dv_; \
            } \
        } }

    TILE(0)

    const int baseA = 508 * t;
    const int baseB = 508 * t + 256;

    h16x2 nA[8], nB[8];
    #define LOAD8(dst, off) { \
        const h16x2* p_ = (const h16x2*)(sDb + (off)); \
        _Pragma("unroll") for (int q = 0; q < 8; ++q) (dst)[q] = p_[q]; }

    LOAD8(nA, baseA)
    LOAD8(nB, baseB)

    float fA[16], fB[16];
    float r1a = LARGE, r1b = LARGE, r2a = LARGE;
    float dg_prev = (t == 0) ? 0.0f : LARGE;
    float carryB = 0.0f;

    #define CONVERT2() { _Pragma("unroll") for (int q = 0; q < 8; ++q) { \
        fA[2*q] = (float)nA[q][0]; fA[2*q+1] = (float)nA[q][1]; \
        fB[2*q] = (float)nB[q][0]; fB[2*q+1] = (float)nB[q][1]; } }

    for (int cc = 0; cc < 15; ++cc) {
        CONVERT2()
        if (cc < 7) TILE(cc + 1)
        LOAD8(nA, baseA + 32 * (cc + 1))
        LOAD8(nB, baseB + 32 * (cc + 1))
        #pragma unroll
        for (int k = 0; k < 16; ++k) {
            float D1v = (k == 0) ? carryB : fB[k - 1];
            STEP(fA[k], D1v)
        }
        carryB = fB[15];
    }
    CONVERT2()
    #pragma unroll
    for (int k = 0; k < 15; ++k) {
        float D1v = (k == 0) ? carryB : fB[k - 1];
        STEP(fA[k], D1v)
    }

    if (t == 63) {
        atomicAdd(&out[w / nbpb], r1b * LN2);
    }
}

extern "C" void kernel_launch(void* const* d_in, const int* in_sizes, int n_in,
                              void* d_out, int out_size, void* d_ws, size_t ws_size,
                              hipStream_t stream) {
    const float* x = (const float*)d_in[0];
    const float* y = (const float*)d_in[1];
    float* out = (float*)d_out;

    const int nblk = in_sizes[0] / (NB * NCH);   // 1024 block-pairs
    const int nbpb = nblk / out_size;            // 32 blocks per batch

    hipMemsetAsync(out, 0, (size_t)out_size * sizeof(float), stream);

    if (ws_size >= (size_t)nblk * PAIRB) {
        h16* Dws = (h16*)d_ws;
        dtw_build<<<nblk, 64, 0, stream>>>(x, y, Dws);
        dtw_dp<<<nblk, 64, 0, stream>>>(Dws, out, nbpb);
    } else {
        dtw_k<<<nblk, 64, 0, stream>>>(x, y, out, nbpb);
    }
}